// Round 3
// baseline (490.929 us; speedup 1.0000x reference)
//
#include <hip/hip_runtime.h>
#include <stdint.h>

// TopKMS (OHEM top-k MSE): per-row MSE over [N, 512] fp32, mean of top-30% rows.
// R9: R8 post-mortem -- VGPR_Count=24 proves the compiler batched the 8
// "straight-line" loads into pairs (32 landing regs needed, 24 allocated):
// MLP destroyed again, 2.87 TB/s effective. Also totals reconcile only with
// ~154 us of poison fills per iteration (fixed floor); and with 32 rows/block
// the B1 LDS hist dedupes nothing.
// Changes: (1) FUSE A+B1: lane0 histograms each row MSE directly via
// fire-and-forget global atomics (spread over the whole kernel -> no
// contention); rowmse buffer and hist_kernel deleted; hist zeroed by a 32KB
// hipMemsetAsync. (2) MLP via loop skew: each wave owns 8 contiguous rows;
// iter r issues row r+1's 4 loads, sched_barrier(0), consumes row r (7 VALU
// ops); all 8 shfl-reductions deferred to an interleaved epilogue so the load
// stream never waits on shuffle latency. Double-buffered landing regs,
// compile-time indices only.

#define D_FEAT 512
#define NBINS 4096          // 256 bins/octave over [2^-8, 2^8)
#define HIST_SHIFT 15       // 8 mantissa bits
#define HIST_BASE (119 << 8)
#define A_THREADS 256
#define ROWS_PER_WAVE 8
#define SEL_THREADS 1024

typedef float f32x4 __attribute__((ext_vector_type(4)));

__device__ __forceinline__ float dot4(f32x4 d) {
    return d.x * d.x + d.y * d.y + d.z * d.z + d.w * d.w;
}

// ------ Phase A (fused): per-row MSE -> direct global-atomic histogram ------
__global__ __launch_bounds__(A_THREADS) void fused_mse_hist_kernel(
    const float* __restrict__ input,
    const float* __restrict__ target,
    int n_rows,
    int* __restrict__ g_cnt,
    float* __restrict__ g_sum)
{
    const int lane = threadIdx.x & 63;
    const int wave = (blockIdx.x * A_THREADS + threadIdx.x) >> 6;
    const int base = wave * ROWS_PER_WAVE;
    if (base >= n_rows) return;

    const float inv_d = 1.0f / (float)D_FEAT;
    const int last = n_rows - 1;

    // Double-buffered landing registers (indices all compile-time after unroll).
    f32x4 LA0[2] = {}, LA1[2] = {}, LB0[2] = {}, LB1[2] = {};
    float accs[ROWS_PER_WAVE];

    // Prologue: issue row `base` loads into buffer 0.
    {
        const int r0 = base;
        const f32x4* a = (const f32x4*)(input  + (size_t)r0 * D_FEAT);
        const f32x4* b = (const f32x4*)(target + (size_t)r0 * D_FEAT);
        LA0[0] = a[lane];
        LA1[0] = a[lane + 64];
        LB0[0] = b[lane];
        LB1[0] = b[lane + 64];
    }

    #pragma unroll
    for (int r = 0; r < ROWS_PER_WAVE; ++r) {
        const int cur = r & 1;
        const int nxt = cur ^ 1;

        // Issue next row's 4 loads BEFORE consuming the current row.
        if (r + 1 < ROWS_PER_WAVE) {
            int nrow = base + r + 1;
            nrow = nrow > last ? last : nrow;      // clamp (wave-uniform)
            const f32x4* an = (const f32x4*)(input  + (size_t)nrow * D_FEAT);
            const f32x4* bn = (const f32x4*)(target + (size_t)nrow * D_FEAT);
            LA0[nxt] = an[lane];
            LA1[nxt] = an[lane + 64];
            LB0[nxt] = bn[lane];
            LB1[nxt] = bn[lane + 64];
        }
        __builtin_amdgcn_sched_barrier(0);  // pin: loads above, math below

        f32x4 d0 = LA0[cur] - LB0[cur];
        f32x4 d1 = LA1[cur] - LB1[cur];
        accs[r] = dot4(d0) + dot4(d1);
    }

    // Epilogue: 8 interleaved wave reductions (independent chains).
    #pragma unroll
    for (int off = 32; off > 0; off >>= 1) {
        #pragma unroll
        for (int j = 0; j < ROWS_PER_WAVE; ++j)
            accs[j] += __shfl_xor(accs[j], off, 64);
    }

    if (lane == 0) {
        #pragma unroll
        for (int j = 0; j < ROWS_PER_WAVE; ++j) {
            const int row = base + j;
            if (row < n_rows) {
                float v = accs[j] * inv_d;
                uint32_t bits = __float_as_uint(v);
                int bin = (int)(bits >> HIST_SHIFT) - HIST_BASE;
                bin = bin < 0 ? 0 : (bin > NBINS - 1 ? NBINS - 1 : bin);
                atomicAdd(&g_cnt[bin], 1);      // fire-and-forget, no stall
                atomicAdd(&g_sum[bin], v);
            }
        }
    }
}

// --------- Phase B: single-block scan of the 32 KB histogram ----------------
__global__ __launch_bounds__(SEL_THREADS) void scan_select_kernel(
    const int* __restrict__ g_cnt,
    const float* __restrict__ g_sum,
    int k,
    float* __restrict__ out)
{
    __shared__ int   cnt[NBINS];
    __shared__ float sum[NBINS];
    __shared__ int   cs[SEL_THREADS];
    __shared__ float ss[SEL_THREADS];
    const int t = threadIdx.x;

    for (int i = t; i < NBINS; i += SEL_THREADS) {
        cnt[i] = g_cnt[i];
        sum[i] = g_sum[i];
    }
    __syncthreads();

    // descending chunks: thread t owns bins [start - ch + 1, start]
    const int ch = NBINS / SEL_THREADS;   // 4
    const int start = NBINS - 1 - t * ch;

    int   c_t = 0;
    float s_t = 0.0f;
    #pragma unroll
    for (int j = 0; j < ch; ++j) { c_t += cnt[start - j]; s_t += sum[start - j]; }
    cs[t] = c_t;
    ss[t] = s_t;
    __syncthreads();

    // Hillis-Steele inclusive scan (top -> bottom order)
    for (int off = 1; off < SEL_THREADS; off <<= 1) {
        int cv = 0; float sv = 0.0f;
        if (t >= off) { cv = cs[t - off]; sv = ss[t - off]; }
        __syncthreads();
        cs[t] += cv;
        ss[t] += sv;
        __syncthreads();
    }

    const int   c_incl   = cs[t];
    const int   c_before = c_incl - c_t;
    const float s_before = ss[t] - s_t;

    if (c_before < k && k <= c_incl) {
        int   cum = c_before;
        float s   = s_before;
        float result = 0.0f;
        for (int j = 0; j < ch; ++j) {
            int b = start - j;
            int c = cnt[b];
            if (c == 0) continue;
            if (cum + c >= k) {
                int need = k - cum;
                float avg = sum[b] / (float)c;   // bin mean, tighter than center
                result = (s + (float)need * avg) / (float)k;
                break;
            }
            cum += c;
            s   += sum[b];
        }
        out[0] = result;
    }
}

extern "C" void kernel_launch(void* const* d_in, const int* in_sizes, int n_in,
                              void* d_out, int out_size, void* d_ws, size_t ws_size,
                              hipStream_t stream)
{
    const float* input  = (const float*)d_in[0];
    const float* target = (const float*)d_in[1];
    float* out = (float*)d_out;

    const int total  = in_sizes[0];
    const int n_rows = total / D_FEAT;            // 65536
    int k = (int)(0.3 * (double)n_rows);          // matches int(K_FRAC * n)
    if (k < 1) k = 1;
    if (k > n_rows) k = n_rows;

    // Histogram at the start of the workspace: g_cnt[NBINS] then g_sum[NBINS].
    int*   g_cnt = (int*)d_ws;
    float* g_sum = (float*)((char*)d_ws + (size_t)NBINS * sizeof(int));

    // Zero the 32 KB histogram (stream-ordered, graph-capturable).
    hipMemsetAsync(d_ws, 0, (size_t)NBINS * (sizeof(int) + sizeof(float)), stream);

    const int rows_per_block = (A_THREADS / 64) * ROWS_PER_WAVE;            // 32
    const int a_blocks = (n_rows + rows_per_block - 1) / rows_per_block;    // 2048

    fused_mse_hist_kernel<<<a_blocks, A_THREADS, 0, stream>>>(
        input, target, n_rows, g_cnt, g_sum);

    scan_select_kernel<<<1, SEL_THREADS, 0, stream>>>(g_cnt, g_sum, k, out);
}